// Round 3
// baseline (713.361 us; speedup 1.0000x reference)
//
#include <hip/hip_runtime.h>
#include <math.h>

#define BATCH  8192
#define EMBED  768
#define DIMD   512
#define MEDIM  64
#define NSTEP  10

typedef __bf16 bf16x8 __attribute__((ext_vector_type(8)));
typedef float  f32x4  __attribute__((ext_vector_type(4)));

// ---- async global->LDS, 16B/lane; LDS base wave-uniform, HW adds lane*16 ----
__device__ __forceinline__ void load16_lds(const __bf16* g, __bf16* l)
{
    auto* gp = (__attribute__((address_space(1))) char*)(uintptr_t)(const void*)g;
    auto* lp = (__attribute__((address_space(3))) char*)(unsigned int)(uintptr_t)(void*)l;
    __builtin_amdgcn_global_load_lds(gp, lp, 16, 0, 0);
}

// ---------------------------------------------------------------------------
// m97-structure bf16 GEMM: C = act(A[M,K] @ Bt[N,K]^T + bias) -> bf16
// BM=BN=128, BK=32, 256 threads = 4 waves (2x2), 64x64/wave, 4x4 frags.
// ---------------------------------------------------------------------------
#define BM 128
#define BN 128
#define BK 32

template<int ACT>   // 0=none, 1=relu
__global__ __launch_bounds__(256)
void gemm_bf16(const __bf16* __restrict__ A, const __bf16* __restrict__ Bt,
               const float* __restrict__ bias, __bf16* __restrict__ C,
               int M, int N, int K)
{
    __shared__ __bf16 lds[(BM + BN) * BK];   // 16 KB: rows 0..127 A, 128..255 B

    const int tid  = threadIdx.x;
    const int wave = tid >> 6;
    const int lane = tid & 63;
    const int row0 = blockIdx.y * BM;
    const int col0 = blockIdx.x * BN;

    const int wr = (wave >> 1) * 64;
    const int wc = (wave & 1) * 64;
    const int fr = lane & 15;
    const int fk = (lane >> 4) * 8;

    const int srow = lane >> 2;          // staging: row within 16-row call
    const int skk  = (lane & 3) * 8;

    f32x4 acc[4][4] = {};

    for (int k0 = 0; k0 < K; k0 += BK) {
#pragma unroll
        for (int c = wave; c < 16; c += 4) {
            const int r = c * 16 + srow;
            const __bf16* g = (r < BM)
                ? (A  + (size_t)(row0 + r)        * K + k0 + skk)
                : (Bt + (size_t)(col0 + (r - BM)) * K + k0 + skk);
            load16_lds(g, &lds[c * 512]);
        }
        __syncthreads();

        const __bf16* As = lds;
        const __bf16* Bs = lds + BM * BK;
        bf16x8 af[4], bfr[4];
#pragma unroll
        for (int m = 0; m < 4; ++m)
            af[m] = *(const bf16x8*)&As[(wr + m * 16 + fr) * BK + fk];
#pragma unroll
        for (int n = 0; n < 4; ++n)
            bfr[n] = *(const bf16x8*)&Bs[(wc + n * 16 + fr) * BK + fk];
#pragma unroll
        for (int m = 0; m < 4; ++m)
#pragma unroll
            for (int n = 0; n < 4; ++n)
                acc[m][n] = __builtin_amdgcn_mfma_f32_16x16x32_bf16(
                                af[m], bfr[n], acc[m][n], 0, 0, 0);
        __syncthreads();
    }

#pragma unroll
    for (int m = 0; m < 4; ++m) {
#pragma unroll
        for (int n = 0; n < 4; ++n) {
            const int cc = col0 + wc + n * 16 + fr;
            const float bb = bias[cc];
#pragma unroll
            for (int j = 0; j < 4; ++j) {
                const int rr = row0 + wr + m * 16 + (lane >> 4) * 4 + j;
                float v = acc[m][n][j] + bb;
                if (ACT == 1) v = fmaxf(v, 0.0f);
                C[(size_t)rr * N + cc] = (__bf16)v;
            }
        }
    }
}

// ---------------------------------------------------------------------------
// Persistent fused scan: 10 steps of h = tanh(h @ ca_w^T + ca_b + eb_s).
// 256 blocks x 512 threads; 32 rows/block; h lives in LDS (XOR-swizzled);
// ca_w K-tiles staged granule-k-major (conflict-free frag reads).
// ---------------------------------------------------------------------------
#define SROWS 32

__global__ __launch_bounds__(512)
void scan_fused(const __bf16* __restrict__ caw, const float* __restrict__ ca_b,
                const float* __restrict__ start, const __bf16* __restrict__ eb_all,
                __bf16* __restrict__ h_out)
{
    __shared__ __bf16 hb[SROWS * 512];   // 32 KB, granule slot = r*64 + (g^(r&7))
    __shared__ __bf16 bb[512 * 32];      // 32 KB, slot G = kblk*512 + n

    const int tid  = threadIdx.x;
    const int wave = tid >> 6;
    const int lane = tid & 63;
    const int row0 = blockIdx.x * SROWS;
    const int wc   = wave * 64;          // 8 waves cover N=512
    const int fr   = lane & 15;
    const int kb   = lane >> 4;          // k-granule within 32-k window

    // h0 = bf16(start), swizzled into hb
    for (int gi = tid; gi < SROWS * 64; gi += 512) {
        const int r = gi >> 6, g = gi & 63;
        const float4 v0 = ((const float4*)start)[g * 2];
        const float4 v1 = ((const float4*)start)[g * 2 + 1];
        bf16x8 o;
        o[0] = (__bf16)v0.x; o[1] = (__bf16)v0.y; o[2] = (__bf16)v0.z; o[3] = (__bf16)v0.w;
        o[4] = (__bf16)v1.x; o[5] = (__bf16)v1.y; o[6] = (__bf16)v1.z; o[7] = (__bf16)v1.w;
        *(bf16x8*)&hb[(r * 64 + (g ^ (r & 7))) * 8] = o;
    }

    for (int s = 0; s < NSTEP; ++s) {
        __syncthreads();                 // hb ready (init or prev epilogue)
        f32x4 acc[2][4] = {};
        for (int k0 = 0; k0 < DIMD; k0 += 32) {
#pragma unroll
            for (int c = 0; c < 4; ++c) {           // stage 32KB ca_w K-tile
                const int Gbase = c * 512 + wave * 64;
                const int G = Gbase + lane;
                const int n = G & 511, kblk = G >> 9;
                load16_lds(caw + (size_t)n * DIMD + k0 + kblk * 8, &bb[Gbase * 8]);
            }
            __syncthreads();             // vmcnt(0) drained -> bb ready
            bf16x8 af[2], bf[4];
#pragma unroll
            for (int m = 0; m < 2; ++m) {
                const int r = m * 16 + fr;
                const int g = (k0 >> 3) + kb;
                af[m] = *(const bf16x8*)&hb[(r * 64 + (g ^ (r & 7))) * 8];
            }
#pragma unroll
            for (int n = 0; n < 4; ++n)
                bf[n] = *(const bf16x8*)&bb[((kb << 9) + wc + n * 16 + fr) * 8];
#pragma unroll
            for (int m = 0; m < 2; ++m)
#pragma unroll
                for (int n = 0; n < 4; ++n)
                    acc[m][n] = __builtin_amdgcn_mfma_f32_16x16x32_bf16(
                                    af[m], bf[n], acc[m][n], 0, 0, 0);
            __syncthreads();             // bb consumed; also fences hb reads
        }
        // epilogue: after last barrier all hb reads are done -> safe to overwrite
        const __bf16* ebs = eb_all + ((size_t)s * BATCH + row0) * DIMD;
#pragma unroll
        for (int m = 0; m < 2; ++m) {
#pragma unroll
            for (int n = 0; n < 4; ++n) {
                const int cc = wc + n * 16 + fr;
                const float cb = ca_b[cc];
#pragma unroll
                for (int j = 0; j < 4; ++j) {
                    const int rr = m * 16 + (lane >> 4) * 4 + j;
                    float v = acc[m][n][j] + cb + (float)ebs[(size_t)rr * DIMD + cc];
                    const float p = __expf(2.0f * v);      // tanh = 1 - 2/(e^2x+1)
                    v = 1.0f - 2.0f / (p + 1.0f);
                    hb[(rr * 64 + ((cc >> 3) ^ (rr & 7))) * 8 + (cc & 7)] = (__bf16)v;
                }
            }
        }
    }
    __syncthreads();
    for (int gi = tid; gi < SROWS * 64; gi += 512) {
        const int r = gi >> 6, g = gi & 63;
        *(bf16x8*)(h_out + ((size_t)(row0 + r)) * DIMD + g * 8) =
            *(const bf16x8*)&hb[(r * 64 + (g ^ (r & 7))) * 8];
    }
}

// ---- all boards f32 -> bf16 with flag masking, all 10 steps, one launch ----
__global__ __launch_bounds__(256)
void cvt_boards_all(const float* __restrict__ src, const int* __restrict__ flags,
                    __bf16* __restrict__ dst)
{
    const int idx  = blockIdx.x * 256 + threadIdx.x;   // 7,864,320 exact
    const int grow = idx / 96;                          // global row 0..81919
    const int s    = grow >> 13;
    const int b    = grow & 8191;
    float m = 1.0f;
    if (s >= 2) m = flags[(size_t)(s - 2) * BATCH + b] ? 1.0f : 0.0f;
    const float4 v0 = ((const float4*)src)[(size_t)idx * 2];
    const float4 v1 = ((const float4*)src)[(size_t)idx * 2 + 1];
    bf16x8 o;
    o[0] = (__bf16)(v0.x * m); o[1] = (__bf16)(v0.y * m);
    o[2] = (__bf16)(v0.z * m); o[3] = (__bf16)(v0.w * m);
    o[4] = (__bf16)(v1.x * m); o[5] = (__bf16)(v1.y * m);
    o[6] = (__bf16)(v1.z * m); o[7] = (__bf16)(v1.w * m);
    *(bf16x8*)(dst + (size_t)idx * 8) = o;
}

// ---- all weights f32 -> one bf16 pool ----
enum : int { W_RED = 0, W_CA = 393216, W_CB = 655360, W_FC1 = 917504,
             W_FC2 = 1212416, W_FC3 = 1474560, W_FC4 = 1998848,
             W_FC5 = 3047424, W_ME = 3571712, W_TOTAL = 3575808 };

__global__ __launch_bounds__(256)
void cvt_weights(const float* __restrict__ w0, const float* __restrict__ w1,
                 const float* __restrict__ w2, const float* __restrict__ w3,
                 const float* __restrict__ w4, const float* __restrict__ w5,
                 const float* __restrict__ w6, const float* __restrict__ w7,
                 const float* __restrict__ w8, __bf16* __restrict__ dst)
{
    const int idx = blockIdx.x * 256 + threadIdx.x;
    if (idx >= W_TOTAL / 8) return;
    const int e = idx * 8;
    const float* src; int off;
    if      (e < W_CA)  { src = w0; off = W_RED; }
    else if (e < W_CB)  { src = w1; off = W_CA; }
    else if (e < W_FC1) { src = w2; off = W_CB; }
    else if (e < W_FC2) { src = w3; off = W_FC1; }
    else if (e < W_FC3) { src = w4; off = W_FC2; }
    else if (e < W_FC4) { src = w5; off = W_FC3; }
    else if (e < W_FC5) { src = w6; off = W_FC4; }
    else if (e < W_ME)  { src = w7; off = W_FC5; }
    else                { src = w8; off = W_ME; }
    const float4 v0 = ((const float4*)(src + (e - off)))[0];
    const float4 v1 = ((const float4*)(src + (e - off)))[1];
    bf16x8 o;
    o[0] = (__bf16)v0.x; o[1] = (__bf16)v0.y; o[2] = (__bf16)v0.z; o[3] = (__bf16)v0.w;
    o[4] = (__bf16)v1.x; o[5] = (__bf16)v1.y; o[6] = (__bf16)v1.z; o[7] = (__bf16)v1.w;
    *(bf16x8*)(dst + (size_t)e) = o;
}

// ---- xcat[b] = [h[b], move_emb_bf16[moves[b]]] ----
__global__ __launch_bounds__(256)
void build_xcat(const __bf16* __restrict__ h, const __bf16* __restrict__ me,
                const int* __restrict__ moves, __bf16* __restrict__ xcat)
{
    const int idx = blockIdx.x * 256 + threadIdx.x;   // 589,824 exact
    const int b  = idx / 72;
    const int c8 = idx - b * 72;
    bf16x8 v;
    if (c8 < 64) v = ((const bf16x8*)(h + (size_t)b * DIMD))[c8];
    else         v = ((const bf16x8*)(me + (size_t)moves[b] * MEDIM))[c8 - 64];
    ((bf16x8*)(xcat + (size_t)b * (DIMD + MEDIM)))[c8] = v;
}

// ---- out[b] = dot(x5[b,:512], out_w) + out_b ----
__global__ __launch_bounds__(256)
void out_head(const __bf16* __restrict__ x, const float* __restrict__ out_w,
              const float* __restrict__ out_b, float* __restrict__ out)
{
    const int wid  = threadIdx.x >> 6;
    const int lane = threadIdx.x & 63;
    const int row  = blockIdx.x * 4 + wid;
    const bf16x8 xv = *(const bf16x8*)(x + (size_t)row * DIMD + lane * 8);
    const float4 w0 = ((const float4*)out_w)[lane * 2];
    const float4 w1 = ((const float4*)out_w)[lane * 2 + 1];
    float s = (float)xv[0] * w0.x + (float)xv[1] * w0.y + (float)xv[2] * w0.z +
              (float)xv[3] * w0.w + (float)xv[4] * w1.x + (float)xv[5] * w1.y +
              (float)xv[6] * w1.z + (float)xv[7] * w1.w;
#pragma unroll
    for (int off = 32; off; off >>= 1) s += __shfl_down(s, off, 64);
    if (lane == 0) out[row] = s + out_b[0];
}

extern "C" void kernel_launch(void* const* d_in, const int* in_sizes, int n_in,
                              void* d_out, int out_size, void* d_ws, size_t ws_size,
                              hipStream_t stream)
{
    const float* boards  = (const float*)d_in[0];
    const int*   flags   = (const int*)  d_in[1];
    const int*   moves   = (const int*)  d_in[3];
    const float* start   = (const float*)d_in[4];
    const float* red_w   = (const float*)d_in[5];
    const float* red_b   = (const float*)d_in[6];
    const float* ca_w    = (const float*)d_in[7];
    const float* ca_b    = (const float*)d_in[8];
    const float* cb_w    = (const float*)d_in[9];
    const float* cb_b    = (const float*)d_in[10];
    const float* move_emb= (const float*)d_in[11];
    const float* fc1_w   = (const float*)d_in[12];
    const float* fc1_b   = (const float*)d_in[13];
    const float* fc2_w   = (const float*)d_in[14];
    const float* fc2_b   = (const float*)d_in[15];
    const float* fc3_w   = (const float*)d_in[16];
    const float* fc3_b   = (const float*)d_in[17];
    const float* fc4_w   = (const float*)d_in[18];
    const float* fc4_b   = (const float*)d_in[19];
    const float* fc5_w   = (const float*)d_in[20];
    const float* fc5_b   = (const float*)d_in[21];
    const float* out_w   = (const float*)d_in[22];
    const float* out_b   = (const float*)d_in[23];

    __bf16* wsb = (__bf16*)d_ws;
    __bf16* wpool  = wsb;                          //   3,575,808
    __bf16* b_all  = wsb + 3575808;                //  62,914,560  [10*8192][768]
    __bf16* e_all  = wsb + 66490368;               //  41,943,040  [10*8192][512]
    __bf16* eb_all = wsb + 108433408;              //  41,943,040
    __bf16* h      = wsb + 150376448;              //   4,194,304
    __bf16* xcat   = wsb + 154570752;              //   4,718,592
    __bf16* x1     = wsb + 159289344;              //   4,194,304
    __bf16* x2     = wsb + 163483648;              //   4,194,304
    __bf16* x3     = wsb + 167677952;              //   8,388,608
    __bf16* x4     = wsb + 176066560;              //   8,388,608
    __bf16* x5     = wsb + 184455168;              //   4,194,304

    const dim3 blk(256);

    cvt_weights<<<1746, blk, 0, stream>>>(red_w, ca_w, cb_w, fc1_w, fc2_w,
                                          fc3_w, fc4_w, fc5_w, move_emb, wpool);
    cvt_boards_all<<<30720, blk, 0, stream>>>(boards, flags, b_all);

    // batched reducer: e_all = relu(b_all @ red_w^T + red_b), M=81920
    gemm_bf16<1><<<dim3(4, 640), blk, 0, stream>>>(
        b_all, wpool + W_RED, red_b, e_all, NSTEP * BATCH, DIMD, EMBED);
    // batched eb: eb_all = e_all @ cb_w^T + cb_b
    gemm_bf16<0><<<dim3(4, 640), blk, 0, stream>>>(
        e_all, wpool + W_CB, cb_b, eb_all, NSTEP * BATCH, DIMD, DIMD);

    // persistent 10-step scan
    scan_fused<<<BATCH / SROWS, dim3(512), 0, stream>>>(
        wpool + W_CA, ca_b, start, eb_all, h);

    build_xcat<<<2304, blk, 0, stream>>>(h, wpool + W_ME, moves, xcat);

    gemm_bf16<1><<<dim3(4, 64), blk, 0, stream>>>(
        xcat, wpool + W_FC1, fc1_b, x1, BATCH, DIMD, DIMD + MEDIM);
    gemm_bf16<1><<<dim3(4, 64), blk, 0, stream>>>(
        x1, wpool + W_FC2, fc2_b, x2, BATCH, DIMD, DIMD);
    gemm_bf16<1><<<dim3(8, 64), blk, 0, stream>>>(
        x2, wpool + W_FC3, fc3_b, x3, BATCH, 1024, DIMD);
    gemm_bf16<1><<<dim3(8, 64), blk, 0, stream>>>(
        x3, wpool + W_FC4, fc4_b, x4, BATCH, 1024, 1024);
    gemm_bf16<1><<<dim3(4, 64), blk, 0, stream>>>(
        x4, wpool + W_FC5, fc5_b, x5, BATCH, DIMD, 1024);

    out_head<<<BATCH / 4, blk, 0, stream>>>(x5, out_w, out_b, (float*)d_out);
}

// Round 4
// 579.038 us; speedup vs baseline: 1.2320x; 1.2320x over previous
//
#include <hip/hip_runtime.h>
#include <math.h>

#define BATCH  8192
#define EMBED  768
#define DIMD   512
#define MEDIM  64
#define NSTEP  10

typedef __bf16 bf16x8 __attribute__((ext_vector_type(8)));
typedef float  f32x4  __attribute__((ext_vector_type(4)));

// ---- async global->LDS, 16B/lane; LDS base wave-uniform, HW adds lane*16 ----
__device__ __forceinline__ void load16_lds(const __bf16* g, __bf16* l)
{
    auto* gp = (__attribute__((address_space(1))) char*)(uintptr_t)(const void*)g;
    auto* lp = (__attribute__((address_space(3))) char*)(unsigned int)(uintptr_t)(void*)l;
    __builtin_amdgcn_global_load_lds(gp, lp, 16, 0, 0);
}

// ---------------------------------------------------------------------------
// m97-structure bf16 GEMM: C = act(A[M,K] @ Bt[N,K]^T + bias (+ add)) -> bf16
// BM=BN=128, BK=32, 256 threads = 4 waves (2x2), 64x64/wave, 4x4 frags.
// ACT: 0=none, 1=relu, 2=tanh(fast, via __expf).
// ---------------------------------------------------------------------------
#define BM 128
#define BN 128
#define BK 32

template<int ACT, bool ADDEB>
__global__ __launch_bounds__(256)
void gemm_bf16(const __bf16* __restrict__ A, const __bf16* __restrict__ Bt,
               const float* __restrict__ bias, const __bf16* __restrict__ add,
               __bf16* __restrict__ C, int M, int N, int K)
{
    __shared__ __bf16 lds[(BM + BN) * BK];   // 16 KB: rows 0..127 A, 128..255 B

    const int tid  = threadIdx.x;
    const int wave = tid >> 6;
    const int lane = tid & 63;
    const int row0 = blockIdx.y * BM;
    const int col0 = blockIdx.x * BN;

    const int wr = (wave >> 1) * 64;
    const int wc = (wave & 1) * 64;
    const int fr = lane & 15;
    const int fk = (lane >> 4) * 8;

    const int srow = lane >> 2;          // staging: row within 16-row call
    const int skk  = (lane & 3) * 8;

    f32x4 acc[4][4] = {};

    for (int k0 = 0; k0 < K; k0 += BK) {
#pragma unroll
        for (int c = wave; c < 16; c += 4) {
            const int r = c * 16 + srow;
            const __bf16* g = (r < BM)
                ? (A  + (size_t)(row0 + r)        * K + k0 + skk)
                : (Bt + (size_t)(col0 + (r - BM)) * K + k0 + skk);
            load16_lds(g, &lds[c * 512]);
        }
        __syncthreads();

        const __bf16* As = lds;
        const __bf16* Bs = lds + BM * BK;
        bf16x8 af[4], bfr[4];
#pragma unroll
        for (int m = 0; m < 4; ++m)
            af[m] = *(const bf16x8*)&As[(wr + m * 16 + fr) * BK + fk];
#pragma unroll
        for (int n = 0; n < 4; ++n)
            bfr[n] = *(const bf16x8*)&Bs[(wc + n * 16 + fr) * BK + fk];
#pragma unroll
        for (int m = 0; m < 4; ++m)
#pragma unroll
            for (int n = 0; n < 4; ++n)
                acc[m][n] = __builtin_amdgcn_mfma_f32_16x16x32_bf16(
                                af[m], bfr[n], acc[m][n], 0, 0, 0);
        __syncthreads();
    }

#pragma unroll
    for (int m = 0; m < 4; ++m) {
#pragma unroll
        for (int n = 0; n < 4; ++n) {
            const int cc = col0 + wc + n * 16 + fr;
            const float bb = bias[cc];
#pragma unroll
            for (int j = 0; j < 4; ++j) {
                const int rr = row0 + wr + m * 16 + (lane >> 4) * 4 + j;
                float v = acc[m][n][j] + bb;
                if (ADDEB) v += (float)add[(size_t)rr * N + cc];
                if (ACT == 1) v = fmaxf(v, 0.0f);
                if (ACT == 2) {                      // tanh = 1 - 2/(e^2x + 1)
                    const float p = __expf(2.0f * v);
                    v = 1.0f - 2.0f / (p + 1.0f);
                }
                C[(size_t)rr * N + cc] = (__bf16)v;
            }
        }
    }
}

// ---- all boards f32 -> bf16 with flag masking, all 10 steps, one launch ----
__global__ __launch_bounds__(256)
void cvt_boards_all(const float* __restrict__ src, const int* __restrict__ flags,
                    __bf16* __restrict__ dst)
{
    const int idx  = blockIdx.x * 256 + threadIdx.x;   // 7,864,320 exact
    const int grow = idx / 96;                          // global row 0..81919
    const int s    = grow >> 13;
    const int b    = grow & 8191;
    float m = 1.0f;
    if (s >= 2) m = flags[(size_t)(s - 2) * BATCH + b] ? 1.0f : 0.0f;
    const float4 v0 = ((const float4*)src)[(size_t)idx * 2];
    const float4 v1 = ((const float4*)src)[(size_t)idx * 2 + 1];
    bf16x8 o;
    o[0] = (__bf16)(v0.x * m); o[1] = (__bf16)(v0.y * m);
    o[2] = (__bf16)(v0.z * m); o[3] = (__bf16)(v0.w * m);
    o[4] = (__bf16)(v1.x * m); o[5] = (__bf16)(v1.y * m);
    o[6] = (__bf16)(v1.z * m); o[7] = (__bf16)(v1.w * m);
    *(bf16x8*)(dst + (size_t)idx * 8) = o;
}

// ---- all weights f32 -> one bf16 pool ----
enum : int { W_RED = 0, W_CA = 393216, W_CB = 655360, W_FC1 = 917504,
             W_FC2 = 1212416, W_FC3 = 1474560, W_FC4 = 1998848,
             W_FC5 = 3047424, W_ME = 3571712, W_TOTAL = 3575808 };

__global__ __launch_bounds__(256)
void cvt_weights(const float* __restrict__ w0, const float* __restrict__ w1,
                 const float* __restrict__ w2, const float* __restrict__ w3,
                 const float* __restrict__ w4, const float* __restrict__ w5,
                 const float* __restrict__ w6, const float* __restrict__ w7,
                 const float* __restrict__ w8, __bf16* __restrict__ dst)
{
    const int idx = blockIdx.x * 256 + threadIdx.x;
    if (idx >= W_TOTAL / 8) return;
    const int e = idx * 8;
    const float* src; int off;
    if      (e < W_CA)  { src = w0; off = W_RED; }
    else if (e < W_CB)  { src = w1; off = W_CA; }
    else if (e < W_FC1) { src = w2; off = W_CB; }
    else if (e < W_FC2) { src = w3; off = W_FC1; }
    else if (e < W_FC3) { src = w4; off = W_FC2; }
    else if (e < W_FC4) { src = w5; off = W_FC3; }
    else if (e < W_FC5) { src = w6; off = W_FC4; }
    else if (e < W_ME)  { src = w7; off = W_FC5; }
    else                { src = w8; off = W_ME; }
    const float4 v0 = ((const float4*)(src + (e - off)))[0];
    const float4 v1 = ((const float4*)(src + (e - off)))[1];
    bf16x8 o;
    o[0] = (__bf16)v0.x; o[1] = (__bf16)v0.y; o[2] = (__bf16)v0.z; o[3] = (__bf16)v0.w;
    o[4] = (__bf16)v1.x; o[5] = (__bf16)v1.y; o[6] = (__bf16)v1.z; o[7] = (__bf16)v1.w;
    *(bf16x8*)(dst + (size_t)e) = o;
}

// ---- h0[b,:] = bf16(start[:]) ----
__global__ __launch_bounds__(256)
void bcast_h0(const float* __restrict__ start, __bf16* __restrict__ h)
{
    const int idx = blockIdx.x * 256 + threadIdx.x;       // 524288 exact
    const int c8 = idx & 63;
    const float4 v0 = ((const float4*)start)[c8 * 2];
    const float4 v1 = ((const float4*)start)[c8 * 2 + 1];
    bf16x8 o;
    o[0] = (__bf16)v0.x; o[1] = (__bf16)v0.y; o[2] = (__bf16)v0.z; o[3] = (__bf16)v0.w;
    o[4] = (__bf16)v1.x; o[5] = (__bf16)v1.y; o[6] = (__bf16)v1.z; o[7] = (__bf16)v1.w;
    *(bf16x8*)(h + (size_t)idx * 8) = o;
}

// ---- xcat[b] = [h[b], move_emb_bf16[moves[b]]] ----
__global__ __launch_bounds__(256)
void build_xcat(const __bf16* __restrict__ h, const __bf16* __restrict__ me,
                const int* __restrict__ moves, __bf16* __restrict__ xcat)
{
    const int idx = blockIdx.x * 256 + threadIdx.x;   // 589,824 exact
    const int b  = idx / 72;
    const int c8 = idx - b * 72;
    bf16x8 v;
    if (c8 < 64) v = ((const bf16x8*)(h + (size_t)b * DIMD))[c8];
    else         v = ((const bf16x8*)(me + (size_t)moves[b] * MEDIM))[c8 - 64];
    ((bf16x8*)(xcat + (size_t)b * (DIMD + MEDIM)))[c8] = v;
}

// ---- out[b] = dot(x5[b,:512], out_w) + out_b ----
__global__ __launch_bounds__(256)
void out_head(const __bf16* __restrict__ x, const float* __restrict__ out_w,
              const float* __restrict__ out_b, float* __restrict__ out)
{
    const int wid  = threadIdx.x >> 6;
    const int lane = threadIdx.x & 63;
    const int row  = blockIdx.x * 4 + wid;
    const bf16x8 xv = *(const bf16x8*)(x + (size_t)row * DIMD + lane * 8);
    const float4 w0 = ((const float4*)out_w)[lane * 2];
    const float4 w1 = ((const float4*)out_w)[lane * 2 + 1];
    float s = (float)xv[0] * w0.x + (float)xv[1] * w0.y + (float)xv[2] * w0.z +
              (float)xv[3] * w0.w + (float)xv[4] * w1.x + (float)xv[5] * w1.y +
              (float)xv[6] * w1.z + (float)xv[7] * w1.w;
#pragma unroll
    for (int off = 32; off; off >>= 1) s += __shfl_down(s, off, 64);
    if (lane == 0) out[row] = s + out_b[0];
}

extern "C" void kernel_launch(void* const* d_in, const int* in_sizes, int n_in,
                              void* d_out, int out_size, void* d_ws, size_t ws_size,
                              hipStream_t stream)
{
    const float* boards  = (const float*)d_in[0];
    const int*   flags   = (const int*)  d_in[1];
    const int*   moves   = (const int*)  d_in[3];
    const float* start   = (const float*)d_in[4];
    const float* red_w   = (const float*)d_in[5];
    const float* red_b   = (const float*)d_in[6];
    const float* ca_w    = (const float*)d_in[7];
    const float* ca_b    = (const float*)d_in[8];
    const float* cb_w    = (const float*)d_in[9];
    const float* cb_b    = (const float*)d_in[10];
    const float* move_emb= (const float*)d_in[11];
    const float* fc1_w   = (const float*)d_in[12];
    const float* fc1_b   = (const float*)d_in[13];
    const float* fc2_w   = (const float*)d_in[14];
    const float* fc2_b   = (const float*)d_in[15];
    const float* fc3_w   = (const float*)d_in[16];
    const float* fc3_b   = (const float*)d_in[17];
    const float* fc4_w   = (const float*)d_in[18];
    const float* fc4_b   = (const float*)d_in[19];
    const float* fc5_w   = (const float*)d_in[20];
    const float* fc5_b   = (const float*)d_in[21];
    const float* out_w   = (const float*)d_in[22];
    const float* out_b   = (const float*)d_in[23];

    __bf16* wsb = (__bf16*)d_ws;
    __bf16* wpool  = wsb;                          //   3,575,808
    __bf16* b_all  = wsb + 3575808;                //  62,914,560  [10*8192][768]
    __bf16* e_all  = wsb + 66490368;               //  41,943,040  [10*8192][512]
    __bf16* eb_all = wsb + 108433408;              //  41,943,040
    __bf16* hA     = wsb + 150376448;              //   4,194,304
    __bf16* hB     = wsb + 154570752;              //   4,194,304
    __bf16* xcat   = wsb + 158765056;              //   4,718,592
    __bf16* x1     = wsb + 163483648;              //   4,194,304
    __bf16* x2     = wsb + 167677952;              //   4,194,304
    __bf16* x3     = wsb + 171872256;              //   8,388,608
    __bf16* x4     = wsb + 180260864;              //   8,388,608
    __bf16* x5     = wsb + 188649472;              //   4,194,304

    const dim3 blk(256);

    cvt_weights<<<1746, blk, 0, stream>>>(red_w, ca_w, cb_w, fc1_w, fc2_w,
                                          fc3_w, fc4_w, fc5_w, move_emb, wpool);
    cvt_boards_all<<<30720, blk, 0, stream>>>(boards, flags, b_all);
    bcast_h0<<<2048, blk, 0, stream>>>(start, hA);

    // batched reducer: e_all = relu(b_all @ red_w^T + red_b), M=81920
    gemm_bf16<1, false><<<dim3(4, 640), blk, 0, stream>>>(
        b_all, wpool + W_RED, red_b, nullptr, e_all, NSTEP * BATCH, DIMD, EMBED);
    // batched eb: eb_all = e_all @ cb_w^T + cb_b
    gemm_bf16<0, false><<<dim3(4, 640), blk, 0, stream>>>(
        e_all, wpool + W_CB, cb_b, nullptr, eb_all, NSTEP * BATCH, DIMD, DIMD);

    // 10-step scan: h = tanh(h @ ca_w^T + ca_b + eb_s), one GEMM per step
    __bf16* hcur = hA;
    __bf16* hnxt = hB;
    for (int s = 0; s < NSTEP; ++s) {
        const __bf16* ebs = eb_all + (size_t)s * BATCH * DIMD;
        gemm_bf16<2, true><<<dim3(4, 64), blk, 0, stream>>>(
            hcur, wpool + W_CA, ca_b, ebs, hnxt, BATCH, DIMD, DIMD);
        __bf16* t = hcur; hcur = hnxt; hnxt = t;
    }

    build_xcat<<<2304, blk, 0, stream>>>(hcur, wpool + W_ME, moves, xcat);

    gemm_bf16<1, false><<<dim3(4, 64), blk, 0, stream>>>(
        xcat, wpool + W_FC1, fc1_b, nullptr, x1, BATCH, DIMD, DIMD + MEDIM);
    gemm_bf16<1, false><<<dim3(4, 64), blk, 0, stream>>>(
        x1, wpool + W_FC2, fc2_b, nullptr, x2, BATCH, DIMD, DIMD);
    gemm_bf16<1, false><<<dim3(8, 64), blk, 0, stream>>>(
        x2, wpool + W_FC3, fc3_b, nullptr, x3, BATCH, 1024, DIMD);
    gemm_bf16<1, false><<<dim3(8, 64), blk, 0, stream>>>(
        x3, wpool + W_FC4, fc4_b, nullptr, x4, BATCH, 1024, 1024);
    gemm_bf16<1, false><<<dim3(4, 64), blk, 0, stream>>>(
        x4, wpool + W_FC5, fc5_b, nullptr, x5, BATCH, DIMD, 1024);

    out_head<<<BATCH / 4, blk, 0, stream>>>(x5, out_w, out_b, (float*)d_out);
}